// Round 3
// baseline (694.725 us; speedup 1.0000x reference)
//
#include <hip/hip_runtime.h>
#include <math.h>

// Problem constants (from reference): H=1024, B=32, S=2048, 2H=2048.
constexpr int H_  = 1024;
constexpr int B_  = 32;
constexpr int S_  = 2048;
constexpr int K2_ = 2048;   // 2*H
constexpr int HCH = 8;      // number of h-chunks for split-K of v = hidden @ W
constexpr int HC  = H_ / HCH; // 128 h per chunk

// Native vector type: __builtin_nontemporal_load requires scalar/native-vector
// pointee (HIP's float4 is a struct wrapper -> rejected by the builtin).
typedef float fx4 __attribute__((ext_vector_type(4)));

// ---------------------------------------------------------------------------
// Kernel 1: partial v[b,k] = sum_{h in chunk} hidden[b,h] * W[h,k]
// grid (2 kc, 8 hc, 4 bg), 256 threads. Each thread owns 4 consecutive k
// (float4 of W, coalesced 1KB/wave) and 8 batches (acc in 32 VGPRs).
// hidden[b*H+h] is wave-uniform -> compiler emits s_load (free broadcast).
// W re-read 4x across bg blocks is L3-absorbed (W = 8 MB << 256 MB L3).
// ---------------------------------------------------------------------------
__global__ __launch_bounds__(256) void k_proj_part(
    const float* __restrict__ hidden, const float* __restrict__ W,
    float* __restrict__ part)
{
    const int tid = threadIdx.x;
    const int kc  = blockIdx.x;   // 0..1   (k-chunk of 1024)
    const int hc  = blockIdx.y;   // 0..7   (h-chunk of 128)
    const int bg  = blockIdx.z;   // 0..3   (batch group of 8)
    const int k0  = kc * 1024 + tid * 4;

    fx4 acc[8];
    #pragma unroll
    for (int j = 0; j < 8; ++j) acc[j] = (fx4)0.f;

    const int h0 = hc * HC;
    for (int hl = 0; hl < HC; ++hl) {
        const int h = h0 + hl;
        const fx4 w4 = *reinterpret_cast<const fx4*>(W + (size_t)h * K2_ + k0);
        #pragma unroll
        for (int j = 0; j < 8; ++j) {
            const float hv = hidden[(bg * 8 + j) * H_ + h];  // uniform -> s_load
            acc[j] += hv * w4;
        }
    }
    #pragma unroll
    for (int j = 0; j < 8; ++j) {
        const int b = bg * 8 + j;
        *reinterpret_cast<fx4*>(part + ((size_t)hc * B_ + b) * K2_ + k0) = acc[j];
    }
}

// ---------------------------------------------------------------------------
// Kernel 2: v[bk] = sum over 8 h-chunk partials (deterministic, no atomics)
// ---------------------------------------------------------------------------
__global__ __launch_bounds__(256) void k_proj_reduce(
    const float* __restrict__ part, float* __restrict__ v)
{
    const int i = blockIdx.x * 256 + threadIdx.x;   // 0 .. B*2H-1
    float s = 0.f;
    #pragma unroll
    for (int hc = 0; hc < HCH; ++hc) s += part[(size_t)hc * (B_ * K2_) + i];
    v[i] = s;
}

// ---------------------------------------------------------------------------
// Kernel 3 (the 537 MB streaming kernel): one wave per 8 rows, fixed b.
// scores[b,s] = v[b,:] . enc[s,b,:]
//   - v[b] hoisted into 32 VGPRs once per wave (cuts v L2 traffic 8x)
//   - 8 independent acc chains -> deep load pipelining
//   - enc rows are 8KB contiguous; lane reads float4 at [j*64+lane] ->
//     perfectly coalesced 1KB/instruction; nontemporal (zero reuse)
//   - wave mapping b=g&31, sg=g>>5: 8 consecutive blocks sweep a contiguous
//     2MB chunk of enc (DRAM/L2 locality)
// ---------------------------------------------------------------------------
__global__ __launch_bounds__(256) void k_scores(
    const float* __restrict__ enc, const float* __restrict__ v,
    float* __restrict__ scores)
{
    const int lane = threadIdx.x & 63;
    const int widx = threadIdx.x >> 6;
    const int g  = blockIdx.x * 4 + widx;  // wave id, 0..8191
    const int b  = g & (B_ - 1);
    const int sg = g >> 5;                 // 0..255; owns s = sg*8 .. sg*8+7

    const fx4* vp = reinterpret_cast<const fx4*>(v + (size_t)b * K2_);
    fx4 vr[8];
    #pragma unroll
    for (int j = 0; j < 8; ++j) vr[j] = vp[j * 64 + lane];

    float acc[8];
    #pragma unroll
    for (int i = 0; i < 8; ++i) acc[i] = 0.f;

    #pragma unroll
    for (int i = 0; i < 8; ++i) {
        const int s = sg * 8 + i;
        const fx4* ep =
            reinterpret_cast<const fx4*>(enc + ((size_t)s * B_ + b) * K2_);
        #pragma unroll
        for (int j = 0; j < 8; ++j) {
            const fx4 e = __builtin_nontemporal_load(ep + j * 64 + lane);
            acc[i] += e.x * vr[j].x + e.y * vr[j].y + e.z * vr[j].z + e.w * vr[j].w;
        }
    }

    #pragma unroll
    for (int i = 0; i < 8; ++i) {
        float a = acc[i];
        #pragma unroll
        for (int off = 32; off > 0; off >>= 1) a += __shfl_xor(a, off);
        if (lane == 0) scores[(size_t)b * S_ + sg * 8 + i] = a;
    }
}

// ---------------------------------------------------------------------------
// Kernel 4: row softmax over S=2048, one block per b, in-place on d_out.
// (Bias term c[b] = hidden[b].bias is a per-row constant -> softmax-invariant,
//  so it is dropped entirely.)
// ---------------------------------------------------------------------------
__global__ __launch_bounds__(256) void k_softmax(float* __restrict__ io)
{
    const int b   = blockIdx.x;
    const int tid = threadIdx.x;
    const int w    = tid >> 6;
    const int lane = tid & 63;
    __shared__ float wmax[4], wsum[4];

    float x[8];
    float m = -INFINITY;
    #pragma unroll
    for (int i = 0; i < 8; ++i) {
        x[i] = io[(size_t)b * S_ + i * 256 + tid];
        m = fmaxf(m, x[i]);
    }
    #pragma unroll
    for (int off = 32; off > 0; off >>= 1) m = fmaxf(m, __shfl_xor(m, off));
    if (lane == 0) wmax[w] = m;
    __syncthreads();
    m = fmaxf(fmaxf(wmax[0], wmax[1]), fmaxf(wmax[2], wmax[3]));

    float sum = 0.f;
    #pragma unroll
    for (int i = 0; i < 8; ++i) { x[i] = __expf(x[i] - m); sum += x[i]; }
    #pragma unroll
    for (int off = 32; off > 0; off >>= 1) sum += __shfl_xor(sum, off);
    if (lane == 0) wsum[w] = sum;
    __syncthreads();
    sum = wsum[0] + wsum[1] + wsum[2] + wsum[3];

    const float inv = 1.f / sum;
    #pragma unroll
    for (int i = 0; i < 8; ++i)
        io[(size_t)b * S_ + i * 256 + tid] = x[i] * inv;
}

// ---------------------------------------------------------------------------
extern "C" void kernel_launch(void* const* d_in, const int* in_sizes, int n_in,
                              void* d_out, int out_size, void* d_ws, size_t ws_size,
                              hipStream_t stream)
{
    const float* hidden = (const float*)d_in[0];   // [1,B,H]
    const float* enc    = (const float*)d_in[1];   // [S,B,2H]
    const float* W      = (const float*)d_in[2];   // [H,2H]
    // d_in[3] (bias) is unused: softmax is invariant to a per-row constant.

    float* part = (float*)d_ws;                    // [HCH][B][2H] = 2 MB
    float* v    = part + (size_t)HCH * B_ * K2_;   // [B][2H]      = 256 KB
    float* out  = (float*)d_out;                   // [B,1,S]; scores staged here

    dim3 gA(2, HCH, 4);
    k_proj_part<<<gA, 256, 0, stream>>>(hidden, W, part);
    k_proj_reduce<<<(B_ * K2_) / 256, 256, 0, stream>>>(part, v);
    k_scores<<<(S_ * B_ / 8) / 4, 256, 0, stream>>>(enc, v, out);   // 2048 blocks
    k_softmax<<<B_, 256, 0, stream>>>(out);
}

// Round 7
// 673.685 us; speedup vs baseline: 1.0312x; 1.0312x over previous
//
#include <hip/hip_runtime.h>
#include <math.h>

// Problem constants (from reference): H=1024, B=32, S=2048, 2H=2048.
constexpr int H_  = 1024;
constexpr int B_  = 32;
constexpr int S_  = 2048;
constexpr int K2_ = 2048;   // 2*H
constexpr int HCH = 32;     // h-chunks for split-K of v = hidden @ W
constexpr int HC  = H_ / HCH; // 32 h per chunk

// Native vector type: __builtin_nontemporal_load requires scalar/native-vector
// pointee (HIP's float4 is a struct wrapper -> rejected by the builtin).
typedef float fx4 __attribute__((ext_vector_type(4)));

// ---------------------------------------------------------------------------
// Kernel 1: partial v[b,k] = sum_{h in chunk} hidden[b,h] * W[h,k]
// grid (2 kc, 32 hc, 4 bg) = 256 blocks (1/CU), 256 threads. Each thread owns
// 4 consecutive k (fx4 of W, coalesced 1KB/wave) and 8 batches (acc in VGPRs).
// hidden[b*H+h] is wave-uniform -> s_load broadcast. 32 W-loads per wave
// (was 128 with 64 blocks) -> 4x less serial-latency exposure, 4x more TLP.
// ---------------------------------------------------------------------------
__global__ __launch_bounds__(256) void k_proj_part(
    const float* __restrict__ hidden, const float* __restrict__ W,
    float* __restrict__ part)
{
    const int tid = threadIdx.x;
    const int kc  = blockIdx.x;   // 0..1   (k-chunk of 1024)
    const int hc  = blockIdx.y;   // 0..31  (h-chunk of 32)
    const int bg  = blockIdx.z;   // 0..3   (batch group of 8)
    const int k0  = kc * 1024 + tid * 4;

    fx4 acc[8];
    #pragma unroll
    for (int j = 0; j < 8; ++j) acc[j] = (fx4)0.f;

    const int h0 = hc * HC;
    #pragma unroll 4
    for (int hl = 0; hl < HC; ++hl) {
        const int h = h0 + hl;
        const fx4 w4 = *reinterpret_cast<const fx4*>(W + (size_t)h * K2_ + k0);
        #pragma unroll
        for (int j = 0; j < 8; ++j) {
            const float hv = hidden[(bg * 8 + j) * H_ + h];  // uniform -> s_load
            acc[j] += hv * w4;
        }
    }
    #pragma unroll
    for (int j = 0; j < 8; ++j) {
        const int b = bg * 8 + j;
        *reinterpret_cast<fx4*>(part + ((size_t)hc * B_ + b) * K2_ + k0) = acc[j];
    }
}

// ---------------------------------------------------------------------------
// Kernel 2: v[bk] = sum over 32 h-chunk partials (deterministic, no atomics)
// 256 blocks, reads 8MB (L2-resident from kernel 1's writes).
// ---------------------------------------------------------------------------
__global__ __launch_bounds__(256) void k_proj_reduce(
    const float* __restrict__ part, float* __restrict__ v)
{
    const int i = blockIdx.x * 256 + threadIdx.x;   // 0 .. B*2H-1
    float s = 0.f;
    #pragma unroll
    for (int hc = 0; hc < HCH; ++hc) s += part[(size_t)hc * (B_ * K2_) + i];
    v[i] = s;
}

// ---------------------------------------------------------------------------
// Kernel 3 (the 537 MB streaming kernel): one wave per 8 rows, fixed b.
// scores[b,s] = v[b,:] . enc[s,b,:]
//   - v[b] hoisted into 32 VGPRs once per wave (cuts v L2 traffic 8x)
//   - 8 independent acc chains -> deep load pipelining
//   - enc rows are 8KB contiguous; lane reads fx4 at [j*64+lane] ->
//     perfectly coalesced 1KB/instruction; nontemporal (zero reuse)
//   - wave mapping b=g&31, sg=g>>5: 8 consecutive blocks sweep a contiguous
//     2MB chunk of enc (DRAM/L2 locality)
// ---------------------------------------------------------------------------
__global__ __launch_bounds__(256) void k_scores(
    const float* __restrict__ enc, const float* __restrict__ v,
    float* __restrict__ scores)
{
    const int lane = threadIdx.x & 63;
    const int widx = threadIdx.x >> 6;
    const int g  = blockIdx.x * 4 + widx;  // wave id, 0..8191
    const int b  = g & (B_ - 1);
    const int sg = g >> 5;                 // 0..255; owns s = sg*8 .. sg*8+7

    const fx4* vp = reinterpret_cast<const fx4*>(v + (size_t)b * K2_);
    fx4 vr[8];
    #pragma unroll
    for (int j = 0; j < 8; ++j) vr[j] = vp[j * 64 + lane];

    float acc[8];
    #pragma unroll
    for (int i = 0; i < 8; ++i) acc[i] = 0.f;

    #pragma unroll
    for (int i = 0; i < 8; ++i) {
        const int s = sg * 8 + i;
        const fx4* ep =
            reinterpret_cast<const fx4*>(enc + ((size_t)s * B_ + b) * K2_);
        #pragma unroll
        for (int j = 0; j < 8; ++j) {
            const fx4 e = __builtin_nontemporal_load(ep + j * 64 + lane);
            acc[i] += e.x * vr[j].x + e.y * vr[j].y + e.z * vr[j].z + e.w * vr[j].w;
        }
    }

    #pragma unroll
    for (int i = 0; i < 8; ++i) {
        float a = acc[i];
        #pragma unroll
        for (int off = 32; off > 0; off >>= 1) a += __shfl_xor(a, off);
        if (lane == 0) scores[(size_t)b * S_ + sg * 8 + i] = a;
    }
}

// ---------------------------------------------------------------------------
// Kernel 4: row softmax over S=2048, one block per b, in-place on d_out.
// (Bias term c[b] = hidden[b].bias is a per-row constant -> softmax-invariant,
//  so it is dropped entirely.)
// ---------------------------------------------------------------------------
__global__ __launch_bounds__(256) void k_softmax(float* __restrict__ io)
{
    const int b   = blockIdx.x;
    const int tid = threadIdx.x;
    const int w    = tid >> 6;
    const int lane = tid & 63;
    __shared__ float wmax[4], wsum[4];

    float x[8];
    float m = -INFINITY;
    #pragma unroll
    for (int i = 0; i < 8; ++i) {
        x[i] = io[(size_t)b * S_ + i * 256 + tid];
        m = fmaxf(m, x[i]);
    }
    #pragma unroll
    for (int off = 32; off > 0; off >>= 1) m = fmaxf(m, __shfl_xor(m, off));
    if (lane == 0) wmax[w] = m;
    __syncthreads();
    m = fmaxf(fmaxf(wmax[0], wmax[1]), fmaxf(wmax[2], wmax[3]));

    float sum = 0.f;
    #pragma unroll
    for (int i = 0; i < 8; ++i) { x[i] = __expf(x[i] - m); sum += x[i]; }
    #pragma unroll
    for (int off = 32; off > 0; off >>= 1) sum += __shfl_xor(sum, off);
    if (lane == 0) wsum[w] = sum;
    __syncthreads();
    sum = wsum[0] + wsum[1] + wsum[2] + wsum[3];

    const float inv = 1.f / sum;
    #pragma unroll
    for (int i = 0; i < 8; ++i)
        io[(size_t)b * S_ + i * 256 + tid] = x[i] * inv;
}

// ---------------------------------------------------------------------------
extern "C" void kernel_launch(void* const* d_in, const int* in_sizes, int n_in,
                              void* d_out, int out_size, void* d_ws, size_t ws_size,
                              hipStream_t stream)
{
    const float* hidden = (const float*)d_in[0];   // [1,B,H]
    const float* enc    = (const float*)d_in[1];   // [S,B,2H]
    const float* W      = (const float*)d_in[2];   // [H,2H]
    // d_in[3] (bias) is unused: softmax is invariant to a per-row constant.

    float* part = (float*)d_ws;                    // [HCH][B][2H] = 8 MB
    float* v    = part + (size_t)HCH * B_ * K2_;   // [B][2H]      = 256 KB
    float* out  = (float*)d_out;                   // [B,1,S]; scores staged here

    dim3 gA(2, HCH, 4);
    k_proj_part<<<gA, 256, 0, stream>>>(hidden, W, part);
    k_proj_reduce<<<(B_ * K2_) / 256, 256, 0, stream>>>(part, v);
    k_scores<<<(S_ * B_ / 8) / 4, 256, 0, stream>>>(enc, v, out);   // 2048 blocks
    k_softmax<<<B_, 256, 0, stream>>>(out);
}